// Round 4
// baseline (631.411 us; speedup 1.0000x reference)
//
#include <hip/hip_runtime.h>

#define B_ 256
#define D_ 784
#define V_ 128
#define S_ 2
#define BD (B_ * D_)
#define ROWS 4
#define NBLKA 64          // B_ / ROWS
#define NTHRA 512

__device__ __forceinline__ void get_params(const int* kiter, float& ss, float& bal) {
    int k = kiter[0] % 10;
    ss  = (k == 0) ? 0.5f : 0.1f;
    bal = (k == 0) ? 0.9f : 0.6f;
}

__device__ __forceinline__ double wave_red(double v) {
#pragma unroll
    for (int o = 32; o > 0; o >>= 1) v += __shfl_down(v, o, 64);
    return v;
}

// ---------------------------------------------------------------------------
// One-time: Wsym[r][c] = 0.5*(W[r][c] + W[c][r]). 32x32 LDS transpose tiles.
// ---------------------------------------------------------------------------
__global__ __launch_bounds__(256) void symmetrize_k(
    const float* __restrict__ W, float* __restrict__ Wsym)
{
    __shared__ float tile[32][33];
    const int bx = blockIdx.x * 32, by = blockIdx.y * 32;
    const int tx = threadIdx.x & 31, ty4 = (threadIdx.x >> 5) * 4;
#pragma unroll
    for (int i = 0; i < 4; ++i) {
        int r = by + ty4 + i, c = bx + tx;
        tile[ty4 + i][tx] = (r < D_ && c < D_) ? W[r * D_ + c] : 0.f;
    }
    __syncthreads();
#pragma unroll
    for (int i = 0; i < 4; ++i) {
        int r = bx + ty4 + i, c = by + tx;       // tile[tx][ty4+i] == W[c][r]
        if (r < D_ && c < D_)
            Wsym[r * D_ + c] = 0.5f * (W[r * D_ + c] + tile[tx][ty4 + i]);
    }
}

// ---------------------------------------------------------------------------
// Fused GEMM + forward. Block owns ROWS=4 batch rows x ALL 784 columns, so
// the g-row is complete in-register -> no gpart round-trip, no extra launch.
// Thread t owns columns d0=t and d1=t+512 (if <784). A staged in LDS [k][4]
// (one broadcast ds_read_b128 per k); Wsym streams from L2 coalesced.
// ---------------------------------------------------------------------------
__global__ __launch_bounds__(NTHRA) void gemm_fwd_k(
    const int* __restrict__ xin, const float* __restrict__ Wsym,
    const float* __restrict__ bvec, const float* __restrict__ gumbel,
    const int* __restrict__ kiter, int s,
    int* __restrict__ x_delta, double* __restrict__ lpf, double* __restrict__ Exf)
{
    const int bid = blockIdx.x, tid = threadIdx.x;
    const int b0 = bid * ROWS;
    float ss, bal; get_params(kiter, ss, bal);
    const float c2 = 0.5f / ss;

    __shared__ __align__(16) float af[D_][ROWS];   // [k][r], 12.5 KB
    for (int idx = tid; idx < ROWS * D_; idx += NTHRA) {
        int r = idx / D_, k = idx - r * D_;
        af[k][r] = (float)xin[(b0 + r) * D_ + k];
    }
    __syncthreads();

    const int d0 = tid;
    const int d1 = tid + NTHRA;
    const bool has1 = d1 < D_;

    float acc[ROWS][2] = {};
#pragma unroll 4
    for (int k = 0; k < D_; ++k) {
        float4 a4 = *(const float4*)&af[k][0];
        float w0 = Wsym[k * D_ + d0];
        float w1 = has1 ? Wsym[k * D_ + d1] : 0.f;
        acc[0][0] = fmaf(a4.x, w0, acc[0][0]);
        acc[1][0] = fmaf(a4.y, w0, acc[1][0]);
        acc[2][0] = fmaf(a4.z, w0, acc[2][0]);
        acc[3][0] = fmaf(a4.w, w0, acc[3][0]);
        acc[0][1] = fmaf(a4.x, w1, acc[0][1]);
        acc[1][1] = fmaf(a4.y, w1, acc[1][1]);
        acc[2][1] = fmaf(a4.z, w1, acc[2][1]);
        acc[3][1] = fmaf(a4.w, w1, acc[3][1]);
    }

    double lp_acc[ROWS] = {}, e_acc[ROWS] = {};
#pragma unroll
    for (int slot = 0; slot < 2; ++slot) {
        const int d = slot ? d1 : d0;
        if (d < D_) {
            const float bvd = bvec[d];
#pragma unroll
            for (int r = 0; r < ROWS; ++r) {
                const int b = b0 + r;
                const float xfv = af[d][r];
                const float gv = acc[r][slot] + bvd;

                const float a1 = bal * gv;
                const float v0 = xfv + a1 * ss;
                int vm = (int)rintf(v0); vm = min(127, max(0, vm));
                const float dmv = v0 - (float)vm;
                const float Reff = sqrtf(30.0f / c2 + dmv * dmv);
                int lo = max(0, (int)ceilf(v0 - Reff));
                int hi = min(127, (int)floorf(v0 + Reff));
                lo = min(lo, vm); hi = max(hi, vm);

                const float dvm = (float)vm - xfv;
                const float mL = dvm * fmaf(-c2, dvm, a1);   // exact max logit

                const float4* __restrict__ gq =
                    (const float4*)(gumbel + (((size_t)s * B_ + b) * D_ + d) * V_);
                const int q0 = lo >> 2, qh = hi >> 2;        // qh - q0 <= 3
                float4 quad[4];
#pragma unroll
                for (int j = 0; j < 4; ++j) quad[j] = gq[min(q0 + j, qh)];

                float best = -1e30f; int imax = vm;
                float sum0 = 0.f, sum1 = 0.f;
#pragma unroll
                for (int j = 0; j < 4; ++j) {
                    const int qi = q0 + j;
                    const bool qok = qi <= qh;
                    const float qs[4] = {quad[j].x, quad[j].y, quad[j].z, quad[j].w};
#pragma unroll
                    for (int c = 0; c < 4; ++c) {
                        int v = 4 * qi + c;
                        bool ok = qok && v >= lo && v <= hi;
                        float dv = (float)v - xfv;
                        float lg = dv * fmaf(-c2, dv, a1);
                        float y = ok ? (lg + qs[c]) : -1e30f;
                        if (y > best) { best = y; imax = v; }   // np.argmax semantics
                        float e = expf(lg - mL);
                        if (c & 1) sum1 += ok ? e : 0.f; else sum0 += ok ? e : 0.f;
                    }
                }
                float lse = mL + logf(sum0 + sum1);
                float dvc = (float)imax - xfv;
                float lch = dvc * fmaf(-c2, dvc, a1);
                lp_acc[r] += (double)(lch - lse);
                e_acc[r]  += (double)xfv * ((double)gv + (double)bvd);
                x_delta[b * D_ + d] = imax;
            }
        }
    }

    __shared__ double wred2[8][ROWS][2];
    const int lane = tid & 63, wv = tid >> 6;
#pragma unroll
    for (int r = 0; r < ROWS; ++r) {
        double t1 = wave_red(lp_acc[r]);
        double t2 = wave_red(e_acc[r]);
        if (lane == 0) { wred2[wv][r][0] = t1; wred2[wv][r][1] = t2; }
    }
    __syncthreads();
    if (tid < ROWS) {
        double sl = 0, se = 0;
#pragma unroll
        for (int i = 0; i < 8; ++i) { sl += wred2[i][tid][0]; se += wred2[i][tid][1]; }
        lpf[b0 + tid] = sl;
        Exf[b0 + tid] = se;
    }
}

// ---------------------------------------------------------------------------
// Fused GEMM(x_delta) + reverse + MH accept + x update + output.
// ---------------------------------------------------------------------------
__global__ __launch_bounds__(NTHRA) void gemm_rev_k(
    const int* __restrict__ xin, int* __restrict__ x_cur,
    const int* __restrict__ x_delta, const float* __restrict__ Wsym,
    const float* __restrict__ bvec, const float* __restrict__ u,
    const int* __restrict__ kiter, int s, int last,
    const double* __restrict__ lpf, const double* __restrict__ Exf,
    float* __restrict__ out)
{
    const int bid = blockIdx.x, tid = threadIdx.x;
    const int b0 = bid * ROWS;
    float ss, bal; get_params(kiter, ss, bal);
    const float c2 = 0.5f / ss;

    __shared__ __align__(16) float af[D_][ROWS];   // x_delta as float, [k][r]
    for (int idx = tid; idx < ROWS * D_; idx += NTHRA) {
        int r = idx / D_, k = idx - r * D_;
        af[k][r] = (float)x_delta[(b0 + r) * D_ + k];
    }
    __syncthreads();

    const int d0 = tid;
    const int d1 = tid + NTHRA;
    const bool has1 = d1 < D_;

    float acc[ROWS][2] = {};
#pragma unroll 4
    for (int k = 0; k < D_; ++k) {
        float4 a4 = *(const float4*)&af[k][0];
        float w0 = Wsym[k * D_ + d0];
        float w1 = has1 ? Wsym[k * D_ + d1] : 0.f;
        acc[0][0] = fmaf(a4.x, w0, acc[0][0]);
        acc[1][0] = fmaf(a4.y, w0, acc[1][0]);
        acc[2][0] = fmaf(a4.z, w0, acc[2][0]);
        acc[3][0] = fmaf(a4.w, w0, acc[3][0]);
        acc[0][1] = fmaf(a4.x, w1, acc[0][1]);
        acc[1][1] = fmaf(a4.y, w1, acc[1][1]);
        acc[2][1] = fmaf(a4.z, w1, acc[2][1]);
        acc[3][1] = fmaf(a4.w, w1, acc[3][1]);
    }

    double lp_acc[ROWS] = {}, e_acc[ROWS] = {};
    int xi_sav[ROWS][2], xd_sav[ROWS][2];
#pragma unroll
    for (int slot = 0; slot < 2; ++slot) {
        const int d = slot ? d1 : d0;
        if (d < D_) {
            const float bvd = bvec[d];
#pragma unroll
            for (int r = 0; r < ROWS; ++r) {
                const int bd = (b0 + r) * D_ + d;
                const int xi = xin[bd];
                const float xdv = af[d][r];
                xi_sav[r][slot] = xi;
                xd_sav[r][slot] = (int)xdv;
                const float gv = acc[r][slot] + bvd;

                const float a1 = bal * gv;
                const float v0 = xdv + a1 * ss;
                int vm = (int)rintf(v0); vm = min(127, max(0, vm));
                const float dmv = v0 - (float)vm;
                const float Reff = sqrtf(30.0f / c2 + dmv * dmv);
                int lo = max(0, (int)ceilf(v0 - Reff));
                int hi = min(127, (int)floorf(v0 + Reff));
                lo = min(lo, vm); hi = max(hi, vm);

                const float dvm = (float)vm - xdv;
                const float mL = dvm * fmaf(-c2, dvm, a1);
                float sum0 = 0.f, sum1 = 0.f;
#pragma unroll
                for (int j = 0; j < 16; ++j) {       // span <= 12, predicated
                    int v = lo + j;
                    bool ok = v <= hi;
                    float dv = (float)v - xdv;
                    float lg = dv * fmaf(-c2, dv, a1);
                    float e = expf(lg - mL);
                    if (j & 1) sum1 += ok ? e : 0.f; else sum0 += ok ? e : 0.f;
                }
                float lse = mL + logf(sum0 + sum1);
                float dvc = (float)xi - xdv;                 // logp_d gathered at x_cur
                float lch = dvc * fmaf(-c2, dvc, a1);
                lp_acc[r] += (double)(lch - lse);
                e_acc[r]  += (double)xdv * ((double)gv + (double)bvd);
            }
        }
    }

    __shared__ double wred2[8][ROWS][2];
    __shared__ int acc_fl[ROWS];
    __shared__ float la_sh[ROWS];
    const int lane = tid & 63, wv = tid >> 6;
#pragma unroll
    for (int r = 0; r < ROWS; ++r) {
        double t1 = wave_red(lp_acc[r]);
        double t2 = wave_red(e_acc[r]);
        if (lane == 0) { wred2[wv][r][0] = t1; wred2[wv][r][1] = t2; }
    }
    __syncthreads();
    if (tid < ROWS) {
        double lpr = 0, exd = 0;
#pragma unroll
        for (int i = 0; i < 8; ++i) { lpr += wred2[i][tid][0]; exd += wred2[i][tid][1]; }
        double la = 0.5 * (exd - Exf[b0 + tid]) + lpr - lpf[b0 + tid];
        acc_fl[tid] = (exp(la) > (double)u[s * B_ + b0 + tid]) ? 1 : 0;
        la_sh[tid] = (float)la;
    }
    __syncthreads();

#pragma unroll
    for (int slot = 0; slot < 2; ++slot) {
        const int d = slot ? d1 : d0;
        if (d < D_) {
#pragma unroll
            for (int r = 0; r < ROWS; ++r) {
                const int bd = (b0 + r) * D_ + d;
                int xn = acc_fl[r] ? xd_sav[r][slot] : xi_sav[r][slot];
                x_cur[bd] = xn;
                if (last) out[bd] = (float)xn;
            }
        }
    }
    if (last && tid < ROWS) out[BD + b0 + tid] = la_sh[tid];
}

// ---------------------------------------------------------------------------
extern "C" void kernel_launch(void* const* d_in, const int* in_sizes, int n_in,
                              void* d_out, int out_size, void* d_ws, size_t ws_size,
                              hipStream_t stream)
{
    const int*   x     = (const int*)d_in[0];
    const float* W     = (const float*)d_in[1];
    const float* bv    = (const float*)d_in[2];
    const float* gum   = (const float*)d_in[3];
    const float* u     = (const float*)d_in[4];
    const int*   kiter = (const int*)d_in[5];
    float* out = (float*)d_out;

    char* w = (char*)d_ws;
    size_t off = 0;
    auto carve = [&](size_t bytes) { void* p = w + off; off += (bytes + 511) & ~511ull; return p; };
    int*    x_cur   = (int*)   carve((size_t)BD * 4);
    int*    x_delta = (int*)   carve((size_t)BD * 4);
    float*  Wsym    = (float*) carve((size_t)D_ * D_ * 4);
    double* lpf     = (double*)carve(B_ * 8);
    double* Exf     = (double*)carve(B_ * 8);
    (void)ws_size; (void)in_sizes; (void)n_in; (void)out_size;

    symmetrize_k<<<dim3(25, 25), 256, 0, stream>>>(W, Wsym);

    for (int s = 0; s < S_; ++s) {
        const int* xin = (s == 0) ? x : x_cur;
        gemm_fwd_k<<<NBLKA, NTHRA, 0, stream>>>(xin, Wsym, bv, gum, kiter, s,
                                                x_delta, lpf, Exf);
        gemm_rev_k<<<NBLKA, NTHRA, 0, stream>>>(xin, x_cur, x_delta, Wsym, bv, u,
                                                kiter, s, (s == S_ - 1) ? 1 : 0,
                                                lpf, Exf, out);
    }
}

// Round 5
// 469.245 us; speedup vs baseline: 1.3456x; 1.3456x over previous
//
#include <hip/hip_runtime.h>

#define B_ 256
#define D_ 784
#define V_ 128
#define S_ 2
#define BD (B_ * D_)
#define ROWS 4
#define NBLKA 64          // B_ / ROWS
#define NTHRA 512
#define KHALF 392         // D_ / 2
#define NCG 196           // D_ / 4 column-quads

__device__ __forceinline__ void get_params(const int* kiter, float& ss, float& bal) {
    int k = kiter[0] % 10;
    ss  = (k == 0) ? 0.5f : 0.1f;
    bal = (k == 0) ? 0.9f : 0.6f;
}

__device__ __forceinline__ double wave_red(double v) {
#pragma unroll
    for (int o = 32; o > 0; o >>= 1) v += __shfl_down(v, o, 64);
    return v;
}

// ---------------------------------------------------------------------------
// One-time: Wsym[r][c] = 0.5*(W[r][c] + W[c][r]). 32x32 LDS transpose tiles.
// ---------------------------------------------------------------------------
__global__ __launch_bounds__(256) void symmetrize_k(
    const float* __restrict__ W, float* __restrict__ Wsym)
{
    __shared__ float tile[32][33];
    const int bx = blockIdx.x * 32, by = blockIdx.y * 32;
    const int tx = threadIdx.x & 31, ty4 = (threadIdx.x >> 5) * 4;
#pragma unroll
    for (int i = 0; i < 4; ++i) {
        int r = by + ty4 + i, c = bx + tx;
        tile[ty4 + i][tx] = (r < D_ && c < D_) ? W[r * D_ + c] : 0.f;
    }
    __syncthreads();
#pragma unroll
    for (int i = 0; i < 4; ++i) {
        int r = bx + ty4 + i, c = by + tx;       // tile[tx][ty4+i] == W[c][r]
        if (r < D_ && c < D_)
            Wsym[r * D_ + c] = 0.5f * (W[r * D_ + c] + tile[tx][ty4 + i]);
    }
}

// ---------------------------------------------------------------------------
// Shared GEMM phase: block owns ROWS=4 batch rows; threads (kc=tid>>8,
// cg=tid&255, cg<196) compute acc[4 rows][4 cols] over a k-half with float4
// Wsym loads (16 FMA per load, 2 independent k-streams). Partials -> LDS.
// ---------------------------------------------------------------------------
__device__ __forceinline__ void gemm_phase(
    const float (*af)[ROWS], const float* __restrict__ Wsym,
    float (*gsum)[ROWS][D_], int tid)
{
    const int kc = tid >> 8, cg = tid & 255;
    if (cg < NCG) {
        const int c0 = cg * 4;
        const int k0 = kc * KHALF;
        float acc[ROWS][4] = {};
#pragma unroll 4
        for (int kk = 0; kk < KHALF; ++kk) {
            const int k = k0 + kk;
            float4 a4 = *(const float4*)&af[k][0];
            float4 w4 = *(const float4*)&Wsym[k * D_ + c0];
            acc[0][0] = fmaf(a4.x, w4.x, acc[0][0]);
            acc[0][1] = fmaf(a4.x, w4.y, acc[0][1]);
            acc[0][2] = fmaf(a4.x, w4.z, acc[0][2]);
            acc[0][3] = fmaf(a4.x, w4.w, acc[0][3]);
            acc[1][0] = fmaf(a4.y, w4.x, acc[1][0]);
            acc[1][1] = fmaf(a4.y, w4.y, acc[1][1]);
            acc[1][2] = fmaf(a4.y, w4.z, acc[1][2]);
            acc[1][3] = fmaf(a4.y, w4.w, acc[1][3]);
            acc[2][0] = fmaf(a4.z, w4.x, acc[2][0]);
            acc[2][1] = fmaf(a4.z, w4.y, acc[2][1]);
            acc[2][2] = fmaf(a4.z, w4.z, acc[2][2]);
            acc[2][3] = fmaf(a4.z, w4.w, acc[2][3]);
            acc[3][0] = fmaf(a4.w, w4.x, acc[3][0]);
            acc[3][1] = fmaf(a4.w, w4.y, acc[3][1]);
            acc[3][2] = fmaf(a4.w, w4.z, acc[3][2]);
            acc[3][3] = fmaf(a4.w, w4.w, acc[3][3]);
        }
#pragma unroll
        for (int r = 0; r < ROWS; ++r)
            *(float4*)&gsum[kc][r][c0] =
                make_float4(acc[r][0], acc[r][1], acc[r][2], acc[r][3]);
    }
    __syncthreads();
}

// ---------------------------------------------------------------------------
// Fused GEMM + forward (categorical sample + lse + per-row reductions).
// ---------------------------------------------------------------------------
__global__ __launch_bounds__(NTHRA) void gemm_fwd_k(
    const int* __restrict__ xin, const float* __restrict__ Wsym,
    const float* __restrict__ bvec, const float* __restrict__ gumbel,
    const int* __restrict__ kiter, int s,
    int* __restrict__ x_delta, double* __restrict__ lpf, double* __restrict__ Exf)
{
    const int bid = blockIdx.x, tid = threadIdx.x;
    const int b0 = bid * ROWS;
    float ss, bal; get_params(kiter, ss, bal);
    const float c2 = 0.5f / ss;

    __shared__ __align__(16) float af[D_][ROWS];       // 12.5 KB
    __shared__ __align__(16) float gsum[2][ROWS][D_];  // 25 KB
    for (int idx = tid; idx < ROWS * D_; idx += NTHRA) {
        int r = idx / D_, k = idx - r * D_;
        af[k][r] = (float)xin[(b0 + r) * D_ + k];
    }
    __syncthreads();

    gemm_phase(af, Wsym, gsum, tid);

    double lp_acc[ROWS] = {}, e_acc[ROWS] = {};
#pragma unroll
    for (int slot = 0; slot < 2; ++slot) {
        const int d = tid + slot * NTHRA;
        if (d < D_) {
            const float bvd = bvec[d];
#pragma unroll
            for (int r = 0; r < ROWS; ++r) {
                const int b = b0 + r;
                const float xfv = af[d][r];
                const float gv = (gsum[0][r][d] + gsum[1][r][d]) + bvd;

                const float a1 = bal * gv;
                const float v0 = xfv + a1 * ss;
                int vm = (int)rintf(v0); vm = min(127, max(0, vm));
                const float dmv = v0 - (float)vm;
                const float Reff = sqrtf(30.0f / c2 + dmv * dmv);
                int lo = max(0, (int)ceilf(v0 - Reff));
                int hi = min(127, (int)floorf(v0 + Reff));
                lo = min(lo, vm); hi = max(hi, vm);

                const float dvm = (float)vm - xfv;
                const float mL = dvm * fmaf(-c2, dvm, a1);   // exact max logit

                const float4* __restrict__ gq =
                    (const float4*)(gumbel + (((size_t)s * B_ + b) * D_ + d) * V_);
                const int q0 = lo >> 2, qh = hi >> 2;        // qh - q0 <= 3
                float4 quad[4];
#pragma unroll
                for (int j = 0; j < 4; ++j) quad[j] = gq[min(q0 + j, qh)];

                float best = -1e30f; int imax = vm;
                float sum0 = 0.f, sum1 = 0.f;
#pragma unroll
                for (int j = 0; j < 4; ++j) {
                    const int qi = q0 + j;
                    const bool qok = qi <= qh;
                    const float qs[4] = {quad[j].x, quad[j].y, quad[j].z, quad[j].w};
#pragma unroll
                    for (int c = 0; c < 4; ++c) {
                        int v = 4 * qi + c;
                        bool ok = qok && v >= lo && v <= hi;
                        float dv = (float)v - xfv;
                        float lg = dv * fmaf(-c2, dv, a1);
                        float y = ok ? (lg + qs[c]) : -1e30f;
                        if (y > best) { best = y; imax = v; }   // np.argmax semantics
                        float e = expf(lg - mL);
                        if (c & 1) sum1 += ok ? e : 0.f; else sum0 += ok ? e : 0.f;
                    }
                }
                float lse = mL + logf(sum0 + sum1);
                float dvc = (float)imax - xfv;
                float lch = dvc * fmaf(-c2, dvc, a1);
                lp_acc[r] += (double)(lch - lse);
                e_acc[r]  += (double)xfv * ((double)gv + (double)bvd);
                x_delta[b * D_ + d] = imax;
            }
        }
    }

    __shared__ double wred2[8][ROWS][2];
    const int lane = tid & 63, wv = tid >> 6;
#pragma unroll
    for (int r = 0; r < ROWS; ++r) {
        double t1 = wave_red(lp_acc[r]);
        double t2 = wave_red(e_acc[r]);
        if (lane == 0) { wred2[wv][r][0] = t1; wred2[wv][r][1] = t2; }
    }
    __syncthreads();
    if (tid < ROWS) {
        double sl = 0, se = 0;
#pragma unroll
        for (int i = 0; i < 8; ++i) { sl += wred2[i][tid][0]; se += wred2[i][tid][1]; }
        lpf[b0 + tid] = sl;
        Exf[b0 + tid] = se;
    }
}

// ---------------------------------------------------------------------------
// Fused GEMM(x_delta) + reverse + MH accept + x update + output.
// ---------------------------------------------------------------------------
__global__ __launch_bounds__(NTHRA) void gemm_rev_k(
    const int* __restrict__ xin, int* __restrict__ x_cur,
    const int* __restrict__ x_delta, const float* __restrict__ Wsym,
    const float* __restrict__ bvec, const float* __restrict__ u,
    const int* __restrict__ kiter, int s, int last,
    const double* __restrict__ lpf, const double* __restrict__ Exf,
    float* __restrict__ out)
{
    const int bid = blockIdx.x, tid = threadIdx.x;
    const int b0 = bid * ROWS;
    float ss, bal; get_params(kiter, ss, bal);
    const float c2 = 0.5f / ss;

    __shared__ __align__(16) float af[D_][ROWS];       // x_delta as float
    __shared__ __align__(16) float gsum[2][ROWS][D_];
    for (int idx = tid; idx < ROWS * D_; idx += NTHRA) {
        int r = idx / D_, k = idx - r * D_;
        af[k][r] = (float)x_delta[(b0 + r) * D_ + k];
    }
    __syncthreads();

    gemm_phase(af, Wsym, gsum, tid);

    double lp_acc[ROWS] = {}, e_acc[ROWS] = {};
    int xi_sav[ROWS][2], xd_sav[ROWS][2];
#pragma unroll
    for (int slot = 0; slot < 2; ++slot) {
        const int d = tid + slot * NTHRA;
        if (d < D_) {
            const float bvd = bvec[d];
#pragma unroll
            for (int r = 0; r < ROWS; ++r) {
                const int bd = (b0 + r) * D_ + d;
                const int xi = xin[bd];
                const float xdv = af[d][r];
                xi_sav[r][slot] = xi;
                xd_sav[r][slot] = (int)xdv;
                const float gv = (gsum[0][r][d] + gsum[1][r][d]) + bvd;

                const float a1 = bal * gv;
                const float v0 = xdv + a1 * ss;
                int vm = (int)rintf(v0); vm = min(127, max(0, vm));
                const float dmv = v0 - (float)vm;
                const float Reff = sqrtf(30.0f / c2 + dmv * dmv);
                int lo = max(0, (int)ceilf(v0 - Reff));
                int hi = min(127, (int)floorf(v0 + Reff));
                lo = min(lo, vm); hi = max(hi, vm);

                const float dvm = (float)vm - xdv;
                const float mL = dvm * fmaf(-c2, dvm, a1);
                float sum0 = 0.f, sum1 = 0.f;
#pragma unroll
                for (int j = 0; j < 16; ++j) {       // span <= 12, predicated
                    int v = lo + j;
                    bool ok = v <= hi;
                    float dv = (float)v - xdv;
                    float lg = dv * fmaf(-c2, dv, a1);
                    float e = expf(lg - mL);
                    if (j & 1) sum1 += ok ? e : 0.f; else sum0 += ok ? e : 0.f;
                }
                float lse = mL + logf(sum0 + sum1);
                float dvc = (float)xi - xdv;                 // logp_d gathered at x_cur
                float lch = dvc * fmaf(-c2, dvc, a1);
                lp_acc[r] += (double)(lch - lse);
                e_acc[r]  += (double)xdv * ((double)gv + (double)bvd);
            }
        }
    }

    __shared__ double wred2[8][ROWS][2];
    __shared__ int acc_fl[ROWS];
    __shared__ float la_sh[ROWS];
    const int lane = tid & 63, wv = tid >> 6;
#pragma unroll
    for (int r = 0; r < ROWS; ++r) {
        double t1 = wave_red(lp_acc[r]);
        double t2 = wave_red(e_acc[r]);
        if (lane == 0) { wred2[wv][r][0] = t1; wred2[wv][r][1] = t2; }
    }
    __syncthreads();
    if (tid < ROWS) {
        double lpr = 0, exd = 0;
#pragma unroll
        for (int i = 0; i < 8; ++i) { lpr += wred2[i][tid][0]; exd += wred2[i][tid][1]; }
        double la = 0.5 * (exd - Exf[b0 + tid]) + lpr - lpf[b0 + tid];
        acc_fl[tid] = (exp(la) > (double)u[s * B_ + b0 + tid]) ? 1 : 0;
        la_sh[tid] = (float)la;
    }
    __syncthreads();

#pragma unroll
    for (int slot = 0; slot < 2; ++slot) {
        const int d = tid + slot * NTHRA;
        if (d < D_) {
#pragma unroll
            for (int r = 0; r < ROWS; ++r) {
                const int bd = (b0 + r) * D_ + d;
                int xn = acc_fl[r] ? xd_sav[r][slot] : xi_sav[r][slot];
                x_cur[bd] = xn;
                if (last) out[bd] = (float)xn;
            }
        }
    }
    if (last && tid < ROWS) out[BD + b0 + tid] = la_sh[tid];
}

// ---------------------------------------------------------------------------
extern "C" void kernel_launch(void* const* d_in, const int* in_sizes, int n_in,
                              void* d_out, int out_size, void* d_ws, size_t ws_size,
                              hipStream_t stream)
{
    const int*   x     = (const int*)d_in[0];
    const float* W     = (const float*)d_in[1];
    const float* bv    = (const float*)d_in[2];
    const float* gum   = (const float*)d_in[3];
    const float* u     = (const float*)d_in[4];
    const int*   kiter = (const int*)d_in[5];
    float* out = (float*)d_out;

    char* w = (char*)d_ws;
    size_t off = 0;
    auto carve = [&](size_t bytes) { void* p = w + off; off += (bytes + 511) & ~511ull; return p; };
    int*    x_cur   = (int*)   carve((size_t)BD * 4);
    int*    x_delta = (int*)   carve((size_t)BD * 4);
    float*  Wsym    = (float*) carve((size_t)D_ * D_ * 4);
    double* lpf     = (double*)carve(B_ * 8);
    double* Exf     = (double*)carve(B_ * 8);
    (void)ws_size; (void)in_sizes; (void)n_in; (void)out_size;

    symmetrize_k<<<dim3(25, 25), 256, 0, stream>>>(W, Wsym);

    for (int s = 0; s < S_; ++s) {
        const int* xin = (s == 0) ? x : x_cur;
        gemm_fwd_k<<<NBLKA, NTHRA, 0, stream>>>(xin, Wsym, bv, gum, kiter, s,
                                                x_delta, lpf, Exf);
        gemm_rev_k<<<NBLKA, NTHRA, 0, stream>>>(xin, x_cur, x_delta, Wsym, bv, u,
                                                kiter, s, (s == S_ - 1) ? 1 : 0,
                                                lpf, Exf, out);
    }
}